// Round 16
// baseline (587.662 us; speedup 1.0000x reference)
//
#include <hip/hip_runtime.h>
#include <hip/hip_bf16.h>

// ---------------------------------------------------------------------------
// HoRA linear: out = x @ (base_w + (150*ifft2(sparse_spectrum)) @ A)^T + b
// M=8192, N=4096, K=4096.  bf16 MFMA GEMM with f32 accumulate.
// 2 launches: prep {blk 0-511: self-compact + 2-stage IFFT + W-build ||
// blk 512-2559: x->bf16} -> r14-proven 256x256 8-wave 8-phase 1-barrier GEMM.
// No grid.sync (r15: cooperative sync cost ~295us of spin — reverted).
// ---------------------------------------------------------------------------

#define OUTF 4096
#define INF  4096
#define NFREQ 10000
#define MDIM 8192
#define KT   (INF / 64)
#define NX4  ((MDIM * INF) / 4)

typedef __attribute__((ext_vector_type(8))) short bf16x8;
typedef __attribute__((ext_vector_type(4))) float f32x4;

__device__ __forceinline__ unsigned int bf16pack2(float a, float b) {
    unsigned int ua = __builtin_bit_cast(unsigned int, a);
    unsigned int ub = __builtin_bit_cast(unsigned int, b);
    ua = (ua + 0x7fffu + ((ua >> 16) & 1u)) >> 16;          // RNE
    ub = (ub + 0x7fffu + ((ub >> 16) & 1u)) & 0xffff0000u;  // RNE, keep high
    return ua | ub;
}

__device__ __forceinline__ void async_copy16(const void* g, void* l) {
    __builtin_amdgcn_global_load_lds(
        (__attribute__((address_space(1))) void*)(g),
        (__attribute__((address_space(3))) void*)(l),
        16, 0, 0);
}

// ---------------------------------------------------------------------------
// K1 (single prep kernel, 2560 blocks x 256):
//  blocks 0-511:  W-build for rows n0..n0+7 (chunk p = n0>>10):
//    (a) 4-wave order-preserving ballot-prefix compact of chunk p -> LDS
//        (~0.5us; same deterministic order as r14 -> bitwise-same B),
//    (b) stage1 IFFT: threads (m_loc,k) scan the list filtering on k
//        (no k-sort needed; summation order = r14's stable bucket order),
//    (c) stage2 16-point transform, (d) W = bf16(bw + B@A).
//  blocks 512-2559: grid-stride x f32 -> bf16.
// LDS ~26.3KB -> 6 blocks/CU; VGPR ~52-70 (two-r-half W-pass).
// ---------------------------------------------------------------------------
__global__ __launch_bounds__(256) void prep_kernel(
        const float* __restrict__ spectrum, const int* __restrict__ idx,
        const float* __restrict__ bw, const float* __restrict__ A,
        unsigned short* __restrict__ W,
        const float4* __restrict__ x4, uint2* __restrict__ xb) {
    __shared__ int2  s_jv[3072];
    __shared__ int   wcnt[4];
    __shared__ int   s_cnt;
    __shared__ float s1re[8][16];
    __shared__ float s1im[8][17];
    __shared__ float sB[8][17];
    const int tid = threadIdx.x;
    if (blockIdx.x >= 512) {
        // ---- x -> bf16 stream (2048 blocks, 16 iters each) ----
        for (int i = (blockIdx.x - 512) * 256 + tid; i < NX4; i += 2048 * 256) {
            float4 v = x4[i];
            xb[i] = make_uint2(bf16pack2(v.x, v.y), bf16pack2(v.z, v.w));
        }
        return;
    }
    const int n0 = blockIdx.x * 8;
    const int p  = n0 >> 10;
    const int wv = tid >> 6, ln = tid & 63;
    // ---- (a) 4-wave order-preserving compact of chunk p into LDS ----
    int cnt = 0;
    for (int i0 = wv * 64; i0 < NFREQ; i0 += 256) {
        const int i = i0 + ln;
        bool m = (i < NFREQ) && ((idx[i] >> 14) == p);
        cnt += __popcll(__ballot(m));
    }
    if (ln == 0) wcnt[wv] = cnt;
    __syncthreads();
    int base = 0;
    for (int w = 0; w < wv; ++w) base += wcnt[w];
    for (int i0 = wv * 64; i0 < NFREQ; i0 += 256) {
        const int i = i0 + ln;
        bool m = false; int id = 0;
        if (i < NFREQ) { id = idx[i]; m = ((id >> 14) == p); }
        unsigned long long bal = __ballot(m);
        if (m) {
            int pos = base + __popcll(bal & ((1ull << ln) - 1ull));
            if (pos < 3072)
                s_jv[pos] = make_int2(id & 16383,
                                      __builtin_bit_cast(int, spectrum[i]));
        }
        base += __popcll(bal);
    }
    if (tid == 0) {
        int t = wcnt[0] + wcnt[1] + wcnt[2] + wcnt[3];
        s_cnt = (t < 3072) ? t : 3072;
    }
    __syncthreads();
    const int cntf = s_cnt;
    // ---- (b) stage1: (m_loc,k) threads scan list, filter by k ----
    if (tid < 128) {
        const int m_loc = tid >> 4;
        const int k     = tid & 15;
        const int m     = (n0 & 1023) + m_loc;
        const float c1  = 6.283185307179586f / 1024.f;
        float re = 0.f, im = 0.f;
        for (int t = 0; t < cntf; ++t) {
            const int2 jv = s_jv[t];          // broadcast read (uniform addr)
            if ((jv.x & 15) == k) {
                const float v = __builtin_bit_cast(float, jv.y);
                const float ang = (float)(((jv.x >> 4) * m) & 1023) * c1;
                re += v * __cosf(ang);
                im += v * __sinf(ang);
            }
        }
        s1re[m_loc][k] = re;
        s1im[m_loc][k] = im;
    }
    __syncthreads();
    // ---- (c) stage2: 16-point transform, real part ----
    if (tid < 128) {
        const int m_loc = tid >> 4;
        const int r     = tid & 15;
        const float c2  = 6.283185307179586f / 16.f;
        float b = 0.f;
#pragma unroll
        for (int k2 = 0; k2 < 16; ++k2) {
            const float ang = (float)((k2 * r) & 15) * c2;
            b += s1re[m_loc][k2] * __cosf(ang) - s1im[m_loc][k2] * __sinf(ang);
        }
        sB[m_loc][r] = b * (150.f / 16384.f);
    }
    __syncthreads();
    // ---- (d) W pass (two r-halves, low VGPR) ----
    const float4* A4  = (const float4*)A;
    const float4* bw4 = (const float4*)bw;
    uint2* W2 = (uint2*)W;
#pragma unroll 1
    for (int q = 0; q < 4; ++q) {
        const int c4 = tid + q * 256;
#pragma unroll 1
        for (int nn = 0; nn < 8; ++nn) {
            const int n = n0 + nn;
            float4 wvv = bw4[n * 1024 + c4];
#pragma unroll 1
            for (int rh = 0; rh < 2; ++rh) {
                float4 a[8];
#pragma unroll
                for (int r = 0; r < 8; ++r) a[r] = A4[(rh * 8 + r) * 1024 + c4];
#pragma unroll
                for (int r = 0; r < 8; ++r) {
                    float s = sB[nn][rh * 8 + r];
                    wvv.x += s * a[r].x; wvv.y += s * a[r].y;
                    wvv.z += s * a[r].z; wvv.w += s * a[r].w;
                }
            }
            W2[n * 1024 + c4] = make_uint2(bf16pack2(wvv.x, wvv.y),
                                           bf16pack2(wvv.z, wvv.w));
        }
    }
}

// ---------------------------------------------------------------------------
// K2: r14-proven 256x256-tile 8-wave bf16 GEMM, 8 phases / 2 K-tiles, one
// barrier per phase, compiler-scheduled lgkm waits (verbatim; 241us,
// MfmaUtil 52, 0 bank conflicts).
// ---------------------------------------------------------------------------
__global__ __launch_bounds__(512, 2) void gemm256_kernel(
        const unsigned short* __restrict__ Xb,
        const unsigned short* __restrict__ Wb,
        const float* __restrict__ bias, float* __restrict__ C) {
    __shared__ __align__(1024) char lds[131072];

    const int tid  = threadIdx.x;
    const int lane = tid & 63;
    const int wid  = tid >> 6;
    const int wm   = wid >> 2;   // 0..1
    const int wn   = wid & 3;    // 0..3

    // XCD-bijective swizzle: nwg=512, divisible by 8.
    int bid = blockIdx.x;
    bid = (bid & 7) * 64 + (bid >> 3);
    const int tm = bid >> 4;     // 0..31  M tile
    const int tn = bid & 15;     // 0..15  N tile
    const int arow0 = tm * 256;
    const int brow0 = tn * 256;

    const int srow  = tid >> 3;
    const int scole = (((tid & 7) * 16) ^ ((srow & 7) << 4)) >> 1;
    const int sldsb = tid * 16;

    const int l15 = lane & 15;
    const int kx0 = ((lane >> 4) * 16) ^ ((lane & 7) << 4);
    const int kx1 = kx0 ^ 64;
    const int abase0 = (wm * 128 + l15) * 128;
    const int bbase0 = 32768 + (wn * 64 + l15) * 128;

    f32x4 acc[8][4] = {};
    bf16x8 af[4][2], bfa[2][2], bfb[2][2];

#define STAGE_HALF(mat, grow0, t, ldsbase) do {                               \
        const unsigned short* _s =                                            \
            (mat) + ((grow0) + srow) * INF + (t) * 64 + scole;                \
        async_copy16(_s, lds + (ldsbase) + sldsb);                            \
        async_copy16(_s + 64 * INF, lds + (ldsbase) + 8192 + sldsb);          \
    } while (0)

#define LDA(DB, m, kh) (*(const bf16x8*)(lds + (DB) + abase0 + (m) * 2048 + ((kh) ? kx1 : kx0)))
#define LDB(DB, n, kh) (*(const bf16x8*)(lds + (DB) + bbase0 + (n) * 2048 + ((kh) ? kx1 : kx0)))
#define MFMA(a, b, c) __builtin_amdgcn_mfma_f32_16x16x32_bf16((a), (b), (c), 0, 0, 0)
#define BARRIER() do { asm volatile("" ::: "memory");                         \
                       __builtin_amdgcn_s_barrier();                          \
                       asm volatile("" ::: "memory"); } while (0)

#define QMFMA(mh, BF)                                                         \
    __builtin_amdgcn_s_setprio(1);                                            \
    _Pragma("unroll") for (int ks = 0; ks < 2; ++ks)                          \
        _Pragma("unroll") for (int m = 0; m < 4; ++m)                         \
            _Pragma("unroll") for (int n = 0; n < 2; ++n)                     \
                acc[(mh) * 4 + m][(BF) * 2 + n] =                             \
                    MFMA(af[m][ks], ((BF) ? bfb : bfa)[n][ks],                \
                         acc[(mh) * 4 + m][(BF) * 2 + n]);                    \
    __builtin_amdgcn_s_setprio(0)

#define RD_AF(DB, mh)                                                         \
    _Pragma("unroll") for (int m = 0; m < 4; ++m) {                           \
        af[m][0] = LDA(DB, (mh) * 4 + m, 0);                                  \
        af[m][1] = LDA(DB, (mh) * 4 + m, 1); }
#define RD_BFA(DB)                                                            \
    _Pragma("unroll") for (int n = 0; n < 2; ++n) {                           \
        bfa[n][0] = LDB(DB, n, 0); bfa[n][1] = LDB(DB, n, 1); }
#define RD_BFB(DB)                                                            \
    _Pragma("unroll") for (int n = 0; n < 2; ++n) {                           \
        bfb[n][0] = LDB(DB, n + 2, 0); bfb[n][1] = LDB(DB, n + 2, 1); }

#define PAIR(CUR, OTH, s) do {                                                \
    RD_BFA(CUR); RD_AF(CUR, 0);                                               \
    STAGE_HALF(Xb, arow0 + 128, (s) + 1, (OTH) + 16384);                      \
    QMFMA(0, 0); BARRIER();                                                   \
    RD_BFB(CUR);                                                              \
    STAGE_HALF(Wb, brow0 + 128, (s) + 1, (OTH) + 49152);                      \
    QMFMA(0, 1); BARRIER();                                                   \
    RD_AF(CUR, 1);                                                            \
    if ((s) + 2 < KT) STAGE_HALF(Wb, brow0, (s) + 2, (CUR) + 32768);          \
    QMFMA(1, 0); BARRIER();                                                   \
    if ((s) + 2 < KT) STAGE_HALF(Xb, arow0, (s) + 2, (CUR) + 0);              \
    QMFMA(1, 1);                                                              \
    if ((s) + 2 < KT) { asm volatile("s_waitcnt vmcnt(4)" ::: "memory"); }    \
    else              { asm volatile("s_waitcnt vmcnt(0)" ::: "memory"); }    \
    BARRIER();                                                                \
    RD_BFA(OTH); RD_AF(OTH, 0);                                               \
    if ((s) + 2 < KT) STAGE_HALF(Xb, arow0 + 128, (s) + 2, (CUR) + 16384);    \
    QMFMA(0, 0); BARRIER();                                                   \
    RD_BFB(OTH);                                                              \
    if ((s) + 2 < KT) STAGE_HALF(Wb, brow0 + 128, (s) + 2, (CUR) + 49152);    \
    QMFMA(0, 1); BARRIER();                                                   \
    RD_AF(OTH, 1);                                                            \
    if ((s) + 3 < KT) STAGE_HALF(Wb, brow0, (s) + 3, (OTH) + 32768);          \
    QMFMA(1, 0); BARRIER();                                                   \
    if ((s) + 3 < KT) STAGE_HALF(Xb, arow0, (s) + 3, (OTH) + 0);              \
    QMFMA(1, 1);                                                              \
    if ((s) + 3 < KT) { asm volatile("s_waitcnt vmcnt(4)" ::: "memory"); }    \
    else              { asm volatile("s_waitcnt vmcnt(0)" ::: "memory"); }    \
    BARRIER();                                                                \
} while (0)

    // ---- prologue: buf0 = tile0 (B0,A0,A1,B1), buf1 = bB0,bA0 of tile1 ----
    STAGE_HALF(Wb, brow0,       0, 32768);
    STAGE_HALF(Xb, arow0,       0, 0);
    STAGE_HALF(Xb, arow0 + 128, 0, 16384);
    STAGE_HALF(Wb, brow0 + 128, 0, 49152);
    STAGE_HALF(Wb, brow0,       1, 65536 + 32768);
    STAGE_HALF(Xb, arow0,       1, 65536 + 0);
    asm volatile("s_waitcnt vmcnt(4)" ::: "memory");
    BARRIER();

    for (int s = 0; s < KT; s += 2)
        PAIR(0, 65536, s);

    // ---- epilogue: C = acc + bias ----
#pragma unroll
    for (int n = 0; n < 4; ++n) {
        const int gcol = brow0 + wn * 64 + n * 16 + l15;
        const float bv = bias[gcol];
#pragma unroll
        for (int m = 0; m < 8; ++m) {
            const int grow = arow0 + wm * 128 + m * 16 + (lane >> 4) * 4;
#pragma unroll
            for (int rg = 0; rg < 4; ++rg)
                C[(grow + rg) * OUTF + gcol] = acc[m][n][rg] + bv;
        }
    }
#undef STAGE_HALF
#undef LDA
#undef LDB
#undef MFMA
#undef BARRIER
#undef QMFMA
#undef RD_AF
#undef RD_BFA
#undef RD_BFB
#undef PAIR
}

// ---------------------------------------------------------------------------
extern "C" void kernel_launch(void* const* d_in, const int* in_sizes, int n_in,
                              void* d_out, int out_size, void* d_ws, size_t ws_size,
                              hipStream_t stream) {
    const float* x    = (const float*)d_in[0];   // [4,2048,4096]
    const float* bw   = (const float*)d_in[1];   // [4096,4096]
    const float* bb   = (const float*)d_in[2];   // [4096]
    const float* spec = (const float*)d_in[3];   // [10000]
    const float* ha   = (const float*)d_in[4];   // [16,4096]
    const int*   idx  = (const int*)d_in[5];     // [10000]
    float* out = (float*)d_out;

    char* ws = (char*)d_ws;
    unsigned short* Wb = (unsigned short*)ws;                  // 32 MB
    unsigned short* Xb = (unsigned short*)(ws + 33554432);     // 64 MB

    prep_kernel<<<2560, 256, 0, stream>>>(
        spec, idx, bw, ha, Wb, (const float4*)x, (uint2*)Xb);
    gemm256_kernel<<<512, 512, 0, stream>>>(Xb, Wb, bb, out);
}

// Round 17
// 545.635 us; speedup vs baseline: 1.0770x; 1.0770x over previous
//
#include <hip/hip_runtime.h>
#include <hip/hip_bf16.h>

// ---------------------------------------------------------------------------
// HoRA linear: out = x @ (base_w + (150*ifft2(sparse_spectrum)) @ A)^T + b
// M=8192, N=4096, K=4096.  bf16 MFMA GEMM with f32 accumulate.
// 2 launches: prep {blk 0-511: self-compact + 2-stage IFFT + W-build ||
// blk 512-2559: x->bf16} -> r14-proven 256x256 8-wave 8-phase 1-barrier GEMM.
// r16 fix: W-pass caches A's 16 rows in registers ONCE PER column-quarter
// (r16 reloaded A inside the nn-loop -> ~2GB redundant L2 traffic, 397us).
// ---------------------------------------------------------------------------

#define OUTF 4096
#define INF  4096
#define NFREQ 10000
#define MDIM 8192
#define KT   (INF / 64)
#define NX4  ((MDIM * INF) / 4)

typedef __attribute__((ext_vector_type(8))) short bf16x8;
typedef __attribute__((ext_vector_type(4))) float f32x4;

__device__ __forceinline__ unsigned int bf16pack2(float a, float b) {
    unsigned int ua = __builtin_bit_cast(unsigned int, a);
    unsigned int ub = __builtin_bit_cast(unsigned int, b);
    ua = (ua + 0x7fffu + ((ua >> 16) & 1u)) >> 16;          // RNE
    ub = (ub + 0x7fffu + ((ub >> 16) & 1u)) & 0xffff0000u;  // RNE, keep high
    return ua | ub;
}

__device__ __forceinline__ void async_copy16(const void* g, void* l) {
    __builtin_amdgcn_global_load_lds(
        (__attribute__((address_space(1))) void*)(g),
        (__attribute__((address_space(3))) void*)(l),
        16, 0, 0);
}

// ---------------------------------------------------------------------------
// K1 (single prep kernel, 2560 blocks x 256):
//  blocks 0-511:  W-build for rows n0..n0+7 (chunk p = n0>>10):
//    (a) 4-wave order-preserving ballot-prefix compact of chunk p -> LDS,
//    (b) stage1 IFFT: threads (m_loc,k) scan the list filtering on k,
//    (c) stage2 16-point transform, (d) W = bf16(bw + B@A) with A's 16 rows
//        register-cached per column-quarter (r14 structure).
//  blocks 512-2559: grid-stride x f32 -> bf16.
// ---------------------------------------------------------------------------
__global__ __launch_bounds__(256) void prep_kernel(
        const float* __restrict__ spectrum, const int* __restrict__ idx,
        const float* __restrict__ bw, const float* __restrict__ A,
        unsigned short* __restrict__ W,
        const float4* __restrict__ x4, uint2* __restrict__ xb) {
    __shared__ int2  s_jv[3072];
    __shared__ int   wcnt[4];
    __shared__ int   s_cnt;
    __shared__ float s1re[8][16];
    __shared__ float s1im[8][17];
    __shared__ float sB[8][17];
    const int tid = threadIdx.x;
    if (blockIdx.x >= 512) {
        // ---- x -> bf16 stream (2048 blocks, 16 iters each) ----
        for (int i = (blockIdx.x - 512) * 256 + tid; i < NX4; i += 2048 * 256) {
            float4 v = x4[i];
            xb[i] = make_uint2(bf16pack2(v.x, v.y), bf16pack2(v.z, v.w));
        }
        return;
    }
    const int n0 = blockIdx.x * 8;
    const int p  = n0 >> 10;
    const int wv = tid >> 6, ln = tid & 63;
    // ---- (a) 4-wave order-preserving compact of chunk p into LDS ----
    int cnt = 0;
    for (int i0 = wv * 64; i0 < NFREQ; i0 += 256) {
        const int i = i0 + ln;
        bool m = (i < NFREQ) && ((idx[i] >> 14) == p);
        cnt += __popcll(__ballot(m));
    }
    if (ln == 0) wcnt[wv] = cnt;
    __syncthreads();
    int base = 0;
    for (int w = 0; w < wv; ++w) base += wcnt[w];
    for (int i0 = wv * 64; i0 < NFREQ; i0 += 256) {
        const int i = i0 + ln;
        bool m = false; int id = 0;
        if (i < NFREQ) { id = idx[i]; m = ((id >> 14) == p); }
        unsigned long long bal = __ballot(m);
        if (m) {
            int pos = base + __popcll(bal & ((1ull << ln) - 1ull));
            if (pos < 3072)
                s_jv[pos] = make_int2(id & 16383,
                                      __builtin_bit_cast(int, spectrum[i]));
        }
        base += __popcll(bal);
    }
    if (tid == 0) {
        int t = wcnt[0] + wcnt[1] + wcnt[2] + wcnt[3];
        s_cnt = (t < 3072) ? t : 3072;
    }
    __syncthreads();
    const int cntf = s_cnt;
    // ---- (b) stage1: (m_loc,k) threads scan list, filter by k ----
    if (tid < 128) {
        const int m_loc = tid >> 4;
        const int k     = tid & 15;
        const int m     = (n0 & 1023) + m_loc;
        const float c1  = 6.283185307179586f / 1024.f;
        float re = 0.f, im = 0.f;
        for (int t = 0; t < cntf; ++t) {
            const int2 jv = s_jv[t];          // broadcast read (uniform addr)
            if ((jv.x & 15) == k) {
                const float v = __builtin_bit_cast(float, jv.y);
                const float ang = (float)(((jv.x >> 4) * m) & 1023) * c1;
                re += v * __cosf(ang);
                im += v * __sinf(ang);
            }
        }
        s1re[m_loc][k] = re;
        s1im[m_loc][k] = im;
    }
    __syncthreads();
    // ---- (c) stage2: 16-point transform, real part ----
    if (tid < 128) {
        const int m_loc = tid >> 4;
        const int r     = tid & 15;
        const float c2  = 6.283185307179586f / 16.f;
        float b = 0.f;
#pragma unroll
        for (int k2 = 0; k2 < 16; ++k2) {
            const float ang = (float)((k2 * r) & 15) * c2;
            b += s1re[m_loc][k2] * __cosf(ang) - s1im[m_loc][k2] * __sinf(ang);
        }
        sB[m_loc][r] = b * (150.f / 16384.f);
    }
    __syncthreads();
    // ---- (d) W pass: a[16] register-cached once per q (r14 structure) ----
    const float4* A4  = (const float4*)A;
    const float4* bw4 = (const float4*)bw;
    uint2* W2 = (uint2*)W;
#pragma unroll 1
    for (int q = 0; q < 4; ++q) {
        const int c4 = tid + q * 256;
        float4 a[16];
#pragma unroll
        for (int r = 0; r < 16; ++r) a[r] = A4[r * 1024 + c4];
#pragma unroll 1
        for (int nn = 0; nn < 8; ++nn) {
            const int n = n0 + nn;
            float4 wvv = bw4[n * 1024 + c4];
#pragma unroll
            for (int r = 0; r < 16; ++r) {
                float s = sB[nn][r];
                wvv.x += s * a[r].x; wvv.y += s * a[r].y;
                wvv.z += s * a[r].z; wvv.w += s * a[r].w;
            }
            W2[n * 1024 + c4] = make_uint2(bf16pack2(wvv.x, wvv.y),
                                           bf16pack2(wvv.z, wvv.w));
        }
    }
}

// ---------------------------------------------------------------------------
// K2: r14-proven 256x256-tile 8-wave bf16 GEMM, 8 phases / 2 K-tiles, one
// barrier per phase, compiler-scheduled lgkm waits (verbatim; 241us,
// MfmaUtil 52, 0 bank conflicts).
// ---------------------------------------------------------------------------
__global__ __launch_bounds__(512, 2) void gemm256_kernel(
        const unsigned short* __restrict__ Xb,
        const unsigned short* __restrict__ Wb,
        const float* __restrict__ bias, float* __restrict__ C) {
    __shared__ __align__(1024) char lds[131072];

    const int tid  = threadIdx.x;
    const int lane = tid & 63;
    const int wid  = tid >> 6;
    const int wm   = wid >> 2;   // 0..1
    const int wn   = wid & 3;    // 0..3

    // XCD-bijective swizzle: nwg=512, divisible by 8.
    int bid = blockIdx.x;
    bid = (bid & 7) * 64 + (bid >> 3);
    const int tm = bid >> 4;     // 0..31  M tile
    const int tn = bid & 15;     // 0..15  N tile
    const int arow0 = tm * 256;
    const int brow0 = tn * 256;

    const int srow  = tid >> 3;
    const int scole = (((tid & 7) * 16) ^ ((srow & 7) << 4)) >> 1;
    const int sldsb = tid * 16;

    const int l15 = lane & 15;
    const int kx0 = ((lane >> 4) * 16) ^ ((lane & 7) << 4);
    const int kx1 = kx0 ^ 64;
    const int abase0 = (wm * 128 + l15) * 128;
    const int bbase0 = 32768 + (wn * 64 + l15) * 128;

    f32x4 acc[8][4] = {};
    bf16x8 af[4][2], bfa[2][2], bfb[2][2];

#define STAGE_HALF(mat, grow0, t, ldsbase) do {                               \
        const unsigned short* _s =                                            \
            (mat) + ((grow0) + srow) * INF + (t) * 64 + scole;                \
        async_copy16(_s, lds + (ldsbase) + sldsb);                            \
        async_copy16(_s + 64 * INF, lds + (ldsbase) + 8192 + sldsb);          \
    } while (0)

#define LDA(DB, m, kh) (*(const bf16x8*)(lds + (DB) + abase0 + (m) * 2048 + ((kh) ? kx1 : kx0)))
#define LDB(DB, n, kh) (*(const bf16x8*)(lds + (DB) + bbase0 + (n) * 2048 + ((kh) ? kx1 : kx0)))
#define MFMA(a, b, c) __builtin_amdgcn_mfma_f32_16x16x32_bf16((a), (b), (c), 0, 0, 0)
#define BARRIER() do { asm volatile("" ::: "memory");                         \
                       __builtin_amdgcn_s_barrier();                          \
                       asm volatile("" ::: "memory"); } while (0)

#define QMFMA(mh, BF)                                                         \
    __builtin_amdgcn_s_setprio(1);                                            \
    _Pragma("unroll") for (int ks = 0; ks < 2; ++ks)                          \
        _Pragma("unroll") for (int m = 0; m < 4; ++m)                         \
            _Pragma("unroll") for (int n = 0; n < 2; ++n)                     \
                acc[(mh) * 4 + m][(BF) * 2 + n] =                             \
                    MFMA(af[m][ks], ((BF) ? bfb : bfa)[n][ks],                \
                         acc[(mh) * 4 + m][(BF) * 2 + n]);                    \
    __builtin_amdgcn_s_setprio(0)

#define RD_AF(DB, mh)                                                         \
    _Pragma("unroll") for (int m = 0; m < 4; ++m) {                           \
        af[m][0] = LDA(DB, (mh) * 4 + m, 0);                                  \
        af[m][1] = LDA(DB, (mh) * 4 + m, 1); }
#define RD_BFA(DB)                                                            \
    _Pragma("unroll") for (int n = 0; n < 2; ++n) {                           \
        bfa[n][0] = LDB(DB, n, 0); bfa[n][1] = LDB(DB, n, 1); }
#define RD_BFB(DB)                                                            \
    _Pragma("unroll") for (int n = 0; n < 2; ++n) {                           \
        bfb[n][0] = LDB(DB, n + 2, 0); bfb[n][1] = LDB(DB, n + 2, 1); }

#define PAIR(CUR, OTH, s) do {                                                \
    RD_BFA(CUR); RD_AF(CUR, 0);                                               \
    STAGE_HALF(Xb, arow0 + 128, (s) + 1, (OTH) + 16384);                      \
    QMFMA(0, 0); BARRIER();                                                   \
    RD_BFB(CUR);                                                              \
    STAGE_HALF(Wb, brow0 + 128, (s) + 1, (OTH) + 49152);                      \
    QMFMA(0, 1); BARRIER();                                                   \
    RD_AF(CUR, 1);                                                            \
    if ((s) + 2 < KT) STAGE_HALF(Wb, brow0, (s) + 2, (CUR) + 32768);          \
    QMFMA(1, 0); BARRIER();                                                   \
    if ((s) + 2 < KT) STAGE_HALF(Xb, arow0, (s) + 2, (CUR) + 0);              \
    QMFMA(1, 1);                                                              \
    if ((s) + 2 < KT) { asm volatile("s_waitcnt vmcnt(4)" ::: "memory"); }    \
    else              { asm volatile("s_waitcnt vmcnt(0)" ::: "memory"); }    \
    BARRIER();                                                                \
    RD_BFA(OTH); RD_AF(OTH, 0);                                               \
    if ((s) + 2 < KT) STAGE_HALF(Xb, arow0 + 128, (s) + 2, (CUR) + 16384);    \
    QMFMA(0, 0); BARRIER();                                                   \
    RD_BFB(OTH);                                                              \
    if ((s) + 2 < KT) STAGE_HALF(Wb, brow0 + 128, (s) + 2, (CUR) + 49152);    \
    QMFMA(0, 1); BARRIER();                                                   \
    RD_AF(OTH, 1);                                                            \
    if ((s) + 3 < KT) STAGE_HALF(Wb, brow0, (s) + 3, (OTH) + 32768);          \
    QMFMA(1, 0); BARRIER();                                                   \
    if ((s) + 3 < KT) STAGE_HALF(Xb, arow0, (s) + 3, (OTH) + 0);              \
    QMFMA(1, 1);                                                              \
    if ((s) + 3 < KT) { asm volatile("s_waitcnt vmcnt(4)" ::: "memory"); }    \
    else              { asm volatile("s_waitcnt vmcnt(0)" ::: "memory"); }    \
    BARRIER();                                                                \
} while (0)

    // ---- prologue: buf0 = tile0 (B0,A0,A1,B1), buf1 = bB0,bA0 of tile1 ----
    STAGE_HALF(Wb, brow0,       0, 32768);
    STAGE_HALF(Xb, arow0,       0, 0);
    STAGE_HALF(Xb, arow0 + 128, 0, 16384);
    STAGE_HALF(Wb, brow0 + 128, 0, 49152);
    STAGE_HALF(Wb, brow0,       1, 65536 + 32768);
    STAGE_HALF(Xb, arow0,       1, 65536 + 0);
    asm volatile("s_waitcnt vmcnt(4)" ::: "memory");
    BARRIER();

    for (int s = 0; s < KT; s += 2)
        PAIR(0, 65536, s);

    // ---- epilogue: C = acc + bias ----
#pragma unroll
    for (int n = 0; n < 4; ++n) {
        const int gcol = brow0 + wn * 64 + n * 16 + l15;
        const float bv = bias[gcol];
#pragma unroll
        for (int m = 0; m < 8; ++m) {
            const int grow = arow0 + wm * 128 + m * 16 + (lane >> 4) * 4;
#pragma unroll
            for (int rg = 0; rg < 4; ++rg)
                C[(grow + rg) * OUTF + gcol] = acc[m][n][rg] + bv;
        }
    }
#undef STAGE_HALF
#undef LDA
#undef LDB
#undef MFMA
#undef BARRIER
#undef QMFMA
#undef RD_AF
#undef RD_BFA
#undef RD_BFB
#undef PAIR
}

// ---------------------------------------------------------------------------
extern "C" void kernel_launch(void* const* d_in, const int* in_sizes, int n_in,
                              void* d_out, int out_size, void* d_ws, size_t ws_size,
                              hipStream_t stream) {
    const float* x    = (const float*)d_in[0];   // [4,2048,4096]
    const float* bw   = (const float*)d_in[1];   // [4096,4096]
    const float* bb   = (const float*)d_in[2];   // [4096]
    const float* spec = (const float*)d_in[3];   // [10000]
    const float* ha   = (const float*)d_in[4];   // [16,4096]
    const int*   idx  = (const int*)d_in[5];     // [10000]
    float* out = (float*)d_out;

    char* ws = (char*)d_ws;
    unsigned short* Wb = (unsigned short*)ws;                  // 32 MB
    unsigned short* Xb = (unsigned short*)(ws + 33554432);     // 64 MB

    prep_kernel<<<2560, 256, 0, stream>>>(
        spec, idx, bw, ha, Wb, (const float4*)x, (uint2*)Xb);
    gemm256_kernel<<<512, 512, 0, stream>>>(Xb, Wb, bb, out);
}

// Round 18
// 373.798 us; speedup vs baseline: 1.5721x; 1.4597x over previous
//
#include <hip/hip_runtime.h>
#include <hip/hip_bf16.h>

// ---------------------------------------------------------------------------
// HoRA linear: out = x @ (base_w + (150*ifft2(sparse_spectrum)) @ A)^T + b
// M=8192, N=4096, K=4096.  bf16 MFMA GEMM with f32 accumulate.
// Session-best configuration (r14, 376.5us measured):
// 3 launches: K1 {compact+k-sort (blk 0-3) || x->bf16 (blk 4-2047)} ->
// K2 {bucketed B-FFT + W build, 512 blk} ->
// GEMM 256x256 8-wave 8-phase, ONE barrier/phase, compiler lgkm waits.
// ---------------------------------------------------------------------------

#define OUTF 4096
#define INF  4096
#define NFREQ 10000
#define MDIM 8192
#define KT   (INF / 64)
#define NX4  ((MDIM * INF) / 4)

typedef __attribute__((ext_vector_type(8))) short bf16x8;
typedef __attribute__((ext_vector_type(4))) float f32x4;

__device__ __forceinline__ unsigned int bf16pack2(float a, float b) {
    unsigned int ua = __builtin_bit_cast(unsigned int, a);
    unsigned int ub = __builtin_bit_cast(unsigned int, b);
    ua = (ua + 0x7fffu + ((ua >> 16) & 1u)) >> 16;          // RNE
    ub = (ub + 0x7fffu + ((ub >> 16) & 1u)) & 0xffff0000u;  // RNE, keep high
    return ua | ub;
}

__device__ __forceinline__ void async_copy16(const void* g, void* l) {
    __builtin_amdgcn_global_load_lds(
        (__attribute__((address_space(1))) void*)(g),
        (__attribute__((address_space(3))) void*)(l),
        16, 0, 0);
}

// ---------------------------------------------------------------------------
// K1: blocks 0-3: compact nnz of chunk p + counting-sort by k (deterministic
// ballot-prefix).  Blocks 4+: grid-stride x f32 -> bf16.
// ---------------------------------------------------------------------------
__global__ __launch_bounds__(256) void k1_compact_cvt_kernel(
        const float* __restrict__ spectrum, const int* __restrict__ idx,
        int2* __restrict__ cjk2, int* __restrict__ boff,
        const float4* __restrict__ x4, uint2* __restrict__ xb) {
    __shared__ int2 s_list[4096];
    __shared__ int  wcnt[4];
    __shared__ int  s_cnt;
    __shared__ int  kcnt[16];
    __shared__ int  kbase[17];
    const int tid = threadIdx.x;
    if (blockIdx.x >= 4) {
        for (int i = (blockIdx.x - 4) * 256 + tid; i < NX4; i += 2044 * 256) {
            float4 v = x4[i];
            xb[i] = make_uint2(bf16pack2(v.x, v.y), bf16pack2(v.z, v.w));
        }
        return;
    }
    const int p  = blockIdx.x;           // chunk 0..3
    const int wv = tid >> 6, ln = tid & 63;
    int cnt = 0;
    for (int i0 = wv * 64; i0 < NFREQ; i0 += 256) {
        const int i = i0 + ln;
        bool m = (i < NFREQ) && ((idx[i] >> 14) == p);
        cnt += __popcll(__ballot(m));
    }
    if (ln == 0) wcnt[wv] = cnt;
    __syncthreads();
    int base = 0;
    for (int w = 0; w < wv; ++w) base += wcnt[w];
    for (int i0 = wv * 64; i0 < NFREQ; i0 += 256) {
        const int i = i0 + ln;
        bool m = false; int id = 0;
        if (i < NFREQ) { id = idx[i]; m = ((id >> 14) == p); }
        unsigned long long bal = __ballot(m);
        if (m) {
            int pos = base + __popcll(bal & ((1ull << ln) - 1ull));
            if (pos < 4096)
                s_list[pos] = make_int2(id & 16383,
                                        __builtin_bit_cast(int, spectrum[i]));
        }
        base += __popcll(bal);
    }
    if (tid == 0) {
        int t = wcnt[0] + wcnt[1] + wcnt[2] + wcnt[3];
        s_cnt = (t < 4096) ? t : 4096;
    }
    __syncthreads();
    const int n = s_cnt;
    for (int q = 0; q < 4; ++q) {
        const int k = wv * 4 + q;
        int c = 0;
        for (int t0 = 0; t0 < n; t0 += 64) {
            const int t = t0 + ln;
            bool m = (t < n) && ((s_list[t].x & 15) == k);
            c += __popcll(__ballot(m));
        }
        if (ln == 0) kcnt[k] = c;
    }
    __syncthreads();
    if (tid == 0) {
        int a = 0;
        for (int k = 0; k < 16; ++k) { kbase[k] = a; a += kcnt[k]; }
        kbase[16] = a;
    }
    __syncthreads();
    for (int q = 0; q < 4; ++q) {
        const int k = wv * 4 + q;
        int b2 = kbase[k];
        for (int t0 = 0; t0 < n; t0 += 64) {
            const int t = t0 + ln;
            bool m = (t < n) && ((s_list[t].x & 15) == k);
            unsigned long long bal = __ballot(m);
            if (m) {
                int pos = b2 + __popcll(bal & ((1ull << ln) - 1ull));
                cjk2[p * 4096 + pos] = make_int2(s_list[t].x >> 4, s_list[t].y);
            }
            b2 += __popcll(bal);
        }
    }
    if (tid < 17) boff[p * 17 + tid] = kbase[tid];
}

// ---------------------------------------------------------------------------
// K2: per block (8 W-rows, chunk p = n0>>10): 2-stage IFFT for its own 8x16
// B sub-block (bucketed stage-1: each (m_loc,k) thread reads only its own
// ~156-entry k-bucket), then W_bf16 = bf16(bw + B@A) with A's 16 rows
// register-cached per column-quarter.
// ---------------------------------------------------------------------------
__global__ __launch_bounds__(256) void k2_w_kernel(
        const int2* __restrict__ cjk2, const int* __restrict__ boff,
        const float* __restrict__ bw, const float* __restrict__ A,
        unsigned short* __restrict__ W) {
    __shared__ int2  s_jv[4096];
    __shared__ float s1re[8][16];
    __shared__ float s1im[8][17];
    __shared__ float sB[8][17];
    const int tid = threadIdx.x;
    const int n0  = blockIdx.x * 8;
    const int p   = n0 >> 10;
    const int cnt = boff[p * 17 + 16];
    for (int t = tid; t < cnt; t += 256) s_jv[t] = cjk2[p * 4096 + t];
    __syncthreads();
    if (tid < 128) {
        const int m_loc = tid >> 4;
        const int k     = tid & 15;
        const int m     = (n0 & 1023) + m_loc;
        const int kb0   = boff[p * 17 + k];
        const int kb1   = boff[p * 17 + k + 1];
        const float c1  = 6.283185307179586f / 1024.f;
        float re = 0.f, im = 0.f;
        for (int t = kb0; t < kb1; ++t) {
            const int2 jv = s_jv[t];
            const float v = __builtin_bit_cast(float, jv.y);
            const float ang = (float)((jv.x * m) & 1023) * c1;
            re += v * __cosf(ang);
            im += v * __sinf(ang);
        }
        s1re[m_loc][k] = re;
        s1im[m_loc][k] = im;
    }
    __syncthreads();
    if (tid < 128) {
        const int m_loc = tid >> 4;
        const int r     = tid & 15;
        const float c2  = 6.283185307179586f / 16.f;
        float b = 0.f;
#pragma unroll
        for (int k2 = 0; k2 < 16; ++k2) {
            const float ang = (float)((k2 * r) & 15) * c2;
            b += s1re[m_loc][k2] * __cosf(ang) - s1im[m_loc][k2] * __sinf(ang);
        }
        sB[m_loc][r] = b * (150.f / 16384.f);
    }
    __syncthreads();
    const float4* A4  = (const float4*)A;
    const float4* bw4 = (const float4*)bw;
    uint2* W2 = (uint2*)W;
#pragma unroll 1
    for (int q = 0; q < 4; ++q) {
        const int c4 = tid + q * 256;
        float4 a[16];
#pragma unroll
        for (int r = 0; r < 16; ++r) a[r] = A4[r * 1024 + c4];
#pragma unroll 1
        for (int nn = 0; nn < 8; ++nn) {
            const int n = n0 + nn;
            float4 wv = bw4[n * 1024 + c4];
#pragma unroll
            for (int r = 0; r < 16; ++r) {
                float s = sB[nn][r];
                wv.x += s * a[r].x; wv.y += s * a[r].y;
                wv.z += s * a[r].z; wv.w += s * a[r].w;
            }
            W2[n * 1024 + c4] = make_uint2(bf16pack2(wv.x, wv.y),
                                           bf16pack2(wv.z, wv.w));
        }
    }
}

// ---------------------------------------------------------------------------
// K3: 256x256-tile 8-wave bf16 GEMM, 8 phases / 2 K-tiles, ONE barrier per
// phase, compiler-scheduled lgkm waits (no forced drain).
// Phase = {reads; stage; setprio(1) MFMA setprio(0); [vmcnt@P4/P8]; barrier}.
// ---------------------------------------------------------------------------
__global__ __launch_bounds__(512, 2) void gemm256_kernel(
        const unsigned short* __restrict__ Xb,
        const unsigned short* __restrict__ Wb,
        const float* __restrict__ bias, float* __restrict__ C) {
    __shared__ __align__(1024) char lds[131072];

    const int tid  = threadIdx.x;
    const int lane = tid & 63;
    const int wid  = tid >> 6;
    const int wm   = wid >> 2;   // 0..1
    const int wn   = wid & 3;    // 0..3

    // XCD-bijective swizzle: nwg=512, divisible by 8.
    int bid = blockIdx.x;
    bid = (bid & 7) * 64 + (bid >> 3);
    const int tm = bid >> 4;     // 0..31  M tile
    const int tn = bid & 15;     // 0..15  N tile
    const int arow0 = tm * 256;
    const int brow0 = tn * 256;

    const int srow  = tid >> 3;
    const int scole = (((tid & 7) * 16) ^ ((srow & 7) << 4)) >> 1;
    const int sldsb = tid * 16;

    const int l15 = lane & 15;
    const int kx0 = ((lane >> 4) * 16) ^ ((lane & 7) << 4);
    const int kx1 = kx0 ^ 64;
    const int abase0 = (wm * 128 + l15) * 128;
    const int bbase0 = 32768 + (wn * 64 + l15) * 128;

    f32x4 acc[8][4] = {};
    bf16x8 af[4][2], bfa[2][2], bfb[2][2];

#define STAGE_HALF(mat, grow0, t, ldsbase) do {                               \
        const unsigned short* _s =                                            \
            (mat) + ((grow0) + srow) * INF + (t) * 64 + scole;                \
        async_copy16(_s, lds + (ldsbase) + sldsb);                            \
        async_copy16(_s + 64 * INF, lds + (ldsbase) + 8192 + sldsb);          \
    } while (0)

#define LDA(DB, m, kh) (*(const bf16x8*)(lds + (DB) + abase0 + (m) * 2048 + ((kh) ? kx1 : kx0)))
#define LDB(DB, n, kh) (*(const bf16x8*)(lds + (DB) + bbase0 + (n) * 2048 + ((kh) ? kx1 : kx0)))
#define MFMA(a, b, c) __builtin_amdgcn_mfma_f32_16x16x32_bf16((a), (b), (c), 0, 0, 0)
#define BARRIER() do { asm volatile("" ::: "memory");                         \
                       __builtin_amdgcn_s_barrier();                          \
                       asm volatile("" ::: "memory"); } while (0)

#define QMFMA(mh, BF)                                                         \
    __builtin_amdgcn_s_setprio(1);                                            \
    _Pragma("unroll") for (int ks = 0; ks < 2; ++ks)                          \
        _Pragma("unroll") for (int m = 0; m < 4; ++m)                         \
            _Pragma("unroll") for (int n = 0; n < 2; ++n)                     \
                acc[(mh) * 4 + m][(BF) * 2 + n] =                             \
                    MFMA(af[m][ks], ((BF) ? bfb : bfa)[n][ks],                \
                         acc[(mh) * 4 + m][(BF) * 2 + n]);                    \
    __builtin_amdgcn_s_setprio(0)

#define RD_AF(DB, mh)                                                         \
    _Pragma("unroll") for (int m = 0; m < 4; ++m) {                           \
        af[m][0] = LDA(DB, (mh) * 4 + m, 0);                                  \
        af[m][1] = LDA(DB, (mh) * 4 + m, 1); }
#define RD_BFA(DB)                                                            \
    _Pragma("unroll") for (int n = 0; n < 2; ++n) {                           \
        bfa[n][0] = LDB(DB, n, 0); bfa[n][1] = LDB(DB, n, 1); }
#define RD_BFB(DB)                                                            \
    _Pragma("unroll") for (int n = 0; n < 2; ++n) {                           \
        bfb[n][0] = LDB(DB, n + 2, 0); bfb[n][1] = LDB(DB, n + 2, 1); }

#define PAIR(CUR, OTH, s) do {                                                \
    /* P1: reads bfa+af01(E); stage O.A1; Q(0,0)E */                          \
    RD_BFA(CUR); RD_AF(CUR, 0);                                               \
    STAGE_HALF(Xb, arow0 + 128, (s) + 1, (OTH) + 16384);                      \
    QMFMA(0, 0); BARRIER();                                                   \
    /* P2: reads bfb(E); stage O.B1; Q(0,1)E */                               \
    RD_BFB(CUR);                                                              \
    STAGE_HALF(Wb, brow0 + 128, (s) + 1, (OTH) + 49152);                      \
    QMFMA(0, 1); BARRIER();                                                   \
    /* P3: reads af23(E); stage C.B0(E+2); Q(1,0)E */                         \
    RD_AF(CUR, 1);                                                            \
    if ((s) + 2 < KT) STAGE_HALF(Wb, brow0, (s) + 2, (CUR) + 32768);          \
    QMFMA(1, 0); BARRIER();                                                   \
    /* P4: stage C.A0(E+2); Q(1,1)E; vmcnt(4) retires all O halves */         \
    if ((s) + 2 < KT) STAGE_HALF(Xb, arow0, (s) + 2, (CUR) + 0);              \
    QMFMA(1, 1);                                                              \
    if ((s) + 2 < KT) { asm volatile("s_waitcnt vmcnt(4)" ::: "memory"); }    \
    else              { asm volatile("s_waitcnt vmcnt(0)" ::: "memory"); }    \
    BARRIER();                                                                \
    /* P5: reads bfa+af01(O); stage C.A1(E+2); Q(0,0)O */                     \
    RD_BFA(OTH); RD_AF(OTH, 0);                                               \
    if ((s) + 2 < KT) STAGE_HALF(Xb, arow0 + 128, (s) + 2, (CUR) + 16384);    \
    QMFMA(0, 0); BARRIER();                                                   \
    /* P6: reads bfb(O); stage C.B1(E+2); Q(0,1)O */                          \
    RD_BFB(OTH);                                                              \
    if ((s) + 2 < KT) STAGE_HALF(Wb, brow0 + 128, (s) + 2, (CUR) + 49152);    \
    QMFMA(0, 1); BARRIER();                                                   \
    /* P7: reads af23(O); stage O.B0(E+3); Q(1,0)O */                         \
    RD_AF(OTH, 1);                                                            \
    if ((s) + 3 < KT) STAGE_HALF(Wb, brow0, (s) + 3, (OTH) + 32768);          \
    QMFMA(1, 0); BARRIER();                                                   \
    /* P8: stage O.A0(E+3); Q(1,1)O; vmcnt(4) retires all E+2 halves */       \
    if ((s) + 3 < KT) STAGE_HALF(Xb, arow0, (s) + 3, (OTH) + 0);              \
    QMFMA(1, 1);                                                              \
    if ((s) + 3 < KT) { asm volatile("s_waitcnt vmcnt(4)" ::: "memory"); }    \
    else              { asm volatile("s_waitcnt vmcnt(0)" ::: "memory"); }    \
    BARRIER();                                                                \
} while (0)

    // ---- prologue: buf0 = tile0 (B0,A0,A1,B1), buf1 = bB0,bA0 of tile1 ----
    STAGE_HALF(Wb, brow0,       0, 32768);
    STAGE_HALF(Xb, arow0,       0, 0);
    STAGE_HALF(Xb, arow0 + 128, 0, 16384);
    STAGE_HALF(Wb, brow0 + 128, 0, 49152);
    STAGE_HALF(Wb, brow0,       1, 65536 + 32768);
    STAGE_HALF(Xb, arow0,       1, 65536 + 0);
    asm volatile("s_waitcnt vmcnt(4)" ::: "memory");
    BARRIER();

    for (int s = 0; s < KT; s += 2)
        PAIR(0, 65536, s);

    // ---- epilogue: C = acc + bias ----
#pragma unroll
    for (int n = 0; n < 4; ++n) {
        const int gcol = brow0 + wn * 64 + n * 16 + l15;
        const float bv = bias[gcol];
#pragma unroll
        for (int m = 0; m < 8; ++m) {
            const int grow = arow0 + wm * 128 + m * 16 + (lane >> 4) * 4;
#pragma unroll
            for (int rg = 0; rg < 4; ++rg)
                C[(grow + rg) * OUTF + gcol] = acc[m][n][rg] + bv;
        }
    }
#undef STAGE_HALF
#undef LDA
#undef LDB
#undef MFMA
#undef BARRIER
#undef QMFMA
#undef RD_AF
#undef RD_BFA
#undef RD_BFB
#undef PAIR
}

// ---------------------------------------------------------------------------
extern "C" void kernel_launch(void* const* d_in, const int* in_sizes, int n_in,
                              void* d_out, int out_size, void* d_ws, size_t ws_size,
                              hipStream_t stream) {
    const float* x    = (const float*)d_in[0];   // [4,2048,4096]
    const float* bw   = (const float*)d_in[1];   // [4096,4096]
    const float* bb   = (const float*)d_in[2];   // [4096]
    const float* spec = (const float*)d_in[3];   // [10000]
    const float* ha   = (const float*)d_in[4];   // [16,4096]
    const int*   idx  = (const int*)d_in[5];     // [10000]
    float* out = (float*)d_out;

    char* ws = (char*)d_ws;
    unsigned short* Wb   = (unsigned short*)ws;                  // 32 MB
    unsigned short* Xb   = (unsigned short*)(ws + 33554432);     // 64 MB
    int2*           cjk2 = (int2*)(ws + 100663296);              // 128 KB
    int*            boff = (int*)(ws + 100794368);               // 4 KB

    k1_compact_cvt_kernel<<<2048, 256, 0, stream>>>(
        spec, idx, cjk2, boff, (const float4*)x, (uint2*)Xb);
    k2_w_kernel<<<512, 256, 0, stream>>>(cjk2, boff, bw, ha, Wb);
    gemm256_kernel<<<512, 512, 0, stream>>>(Xb, Wb, bb, out);
}